// Round 1
// baseline (1061.517 us; speedup 1.0000x reference)
//
#include <hip/hip_runtime.h>
#include <hip/hip_bf16.h>

// Problem: MultiHeadAttention  B=4, L=1024, H=16, U=64, D_IN=1024, D_MODEL=1024
// Inputs (fp32): v,k,q (4096x1024), wq,bq,wk,bk,wv,bv (1024x1024 / 1024), wo (1024x64), bo (64)
// Outputs (fp32, concat): out (4096x64) = 262144 floats, attn (4,16,1024,1024) = 67108864 floats
//
// Round 0: correctness-first fp32 baseline.
//   gemm_proj   : X(4096x1024) @ W(1024x1024) + b -> head-split (B,H,L,U)   x3 (q,k,v)
//   gemm_logits : per (b,h): qh(1024x64) @ kh^T -> raw logits*scale into attn buf
//   softmax_rows: in-place row softmax over 1024 (65536 rows)
//   gemm_ctx    : per (b,h): attn(1024x1024) @ vh(1024x64) -> ctx
//   gemm_out    : concat(ctx)(4096x1024) @ wo(1024x64) + bo -> out
// All tiled 64x64 (BK=16), 256 thr, 4x4 micro-tile, LDS rows padded to 68 floats
// (68*4B = 272B, 16B-aligned -> ds_read_b128; conflicts <=2-way = free).

#define LDS_PAD 68

__global__ __launch_bounds__(256) void gemm_proj(const float* __restrict__ X,
                                                 const float* __restrict__ W,
                                                 const float* __restrict__ bias,
                                                 float* __restrict__ Yh) {
    __shared__ float As[16][LDS_PAD];
    __shared__ float Bs[16][LDS_PAD];
    const int t   = threadIdx.x;
    const int tx  = t & 15, ty = t >> 4;
    const int row0 = blockIdx.y * 64;   // M tile (r = b*1024 + l)
    const int col0 = blockIdx.x * 64;   // N tile (c = h*64 + u), h = blockIdx.x

    const int am  = t >> 2, ak4 = t & 3;      // A loader: row am, float4 at k = ak4*4
    const int bk  = t >> 4, bn4 = t & 15;     // B loader: k row bk, float4 at n = bn4*4

    float acc[4][4] = {};
    for (int k0 = 0; k0 < 1024; k0 += 16) {
        float4 a = *(const float4*)&X[(size_t)(row0 + am) * 1024 + k0 + ak4 * 4];
        float4 b = *(const float4*)&W[(size_t)(k0 + bk) * 1024 + col0 + bn4 * 4];
        As[ak4 * 4 + 0][am] = a.x; As[ak4 * 4 + 1][am] = a.y;
        As[ak4 * 4 + 2][am] = a.z; As[ak4 * 4 + 3][am] = a.w;
        Bs[bk][bn4 * 4 + 0] = b.x; Bs[bk][bn4 * 4 + 1] = b.y;
        Bs[bk][bn4 * 4 + 2] = b.z; Bs[bk][bn4 * 4 + 3] = b.w;
        __syncthreads();
#pragma unroll
        for (int kk = 0; kk < 16; ++kk) {
            float av[4], bv[4];
#pragma unroll
            for (int i = 0; i < 4; ++i) av[i] = As[kk][ty * 4 + i];
#pragma unroll
            for (int j = 0; j < 4; ++j) bv[j] = Bs[kk][tx * 4 + j];
#pragma unroll
            for (int i = 0; i < 4; ++i)
#pragma unroll
                for (int j = 0; j < 4; ++j) acc[i][j] += av[i] * bv[j];
        }
        __syncthreads();
    }
    // epilogue: head-split store. h fixed per block = blockIdx.x
    const int h = blockIdx.x;
#pragma unroll
    for (int i = 0; i < 4; ++i) {
        const int r = row0 + ty * 4 + i;
        const int b = r >> 10, l = r & 1023;
        float* dst = &Yh[(size_t)((b * 16 + h) * 1024 + l) * 64];
#pragma unroll
        for (int j = 0; j < 4; ++j) {
            const int u = tx * 4 + j;
            dst[u] = acc[i][j] + bias[col0 + u];
        }
    }
}

__global__ __launch_bounds__(256) void gemm_logits(const float* __restrict__ qh,
                                                   const float* __restrict__ kh,
                                                   float* __restrict__ attn) {
    __shared__ float As[16][LDS_PAD];
    __shared__ float Bs[16][LDS_PAD];
    const int t  = threadIdx.x;
    const int tx = t & 15, ty = t >> 4;
    const int bh = blockIdx.z;
    const int i0 = blockIdx.y * 64;
    const int j0 = blockIdx.x * 64;
    const size_t base = (size_t)bh * 1024 * 64;
    const size_t obase = (size_t)bh * 1024 * 1024;

    const int am = t >> 2, ak4 = t & 3;   // A: qh row am, k = ak4*4
    const int jn = t & 63, kq = t >> 6;   // B: kh row jn, float4 at k = kq*4 (within 16-tile)

    float acc[4][4] = {};
    for (int k0 = 0; k0 < 64; k0 += 16) {
        float4 a = *(const float4*)&qh[base + (size_t)(i0 + am) * 64 + k0 + ak4 * 4];
        float4 b = *(const float4*)&kh[base + (size_t)(j0 + jn) * 64 + k0 + kq * 4];
        As[ak4 * 4 + 0][am] = a.x; As[ak4 * 4 + 1][am] = a.y;
        As[ak4 * 4 + 2][am] = a.z; As[ak4 * 4 + 3][am] = a.w;
        Bs[kq * 4 + 0][jn] = b.x; Bs[kq * 4 + 1][jn] = b.y;
        Bs[kq * 4 + 2][jn] = b.z; Bs[kq * 4 + 3][jn] = b.w;
        __syncthreads();
#pragma unroll
        for (int kk = 0; kk < 16; ++kk) {
            float av[4], bv[4];
#pragma unroll
            for (int i = 0; i < 4; ++i) av[i] = As[kk][ty * 4 + i];
#pragma unroll
            for (int j = 0; j < 4; ++j) bv[j] = Bs[kk][tx * 4 + j];
#pragma unroll
            for (int i = 0; i < 4; ++i)
#pragma unroll
                for (int j = 0; j < 4; ++j) acc[i][j] += av[i] * bv[j];
        }
        __syncthreads();
    }
    const float scale = 0.125f;  // 1/sqrt(64)
#pragma unroll
    for (int i = 0; i < 4; ++i) {
        float* dst = &attn[obase + (size_t)(i0 + ty * 4 + i) * 1024 + j0];
#pragma unroll
        for (int j = 0; j < 4; ++j) dst[tx * 4 + j] = acc[i][j] * scale;
    }
}

__global__ __launch_bounds__(256) void softmax_rows(float* __restrict__ attn) {
    __shared__ float red[256];
    const int t = threadIdx.x;
    float* p = attn + (size_t)blockIdx.x * 1024;
    float4 v = ((float4*)p)[t];
    float m = fmaxf(fmaxf(v.x, v.y), fmaxf(v.z, v.w));
    red[t] = m; __syncthreads();
    for (int s = 128; s > 0; s >>= 1) {
        if (t < s) red[t] = fmaxf(red[t], red[t + s]);
        __syncthreads();
    }
    const float rowmax = red[0];
    __syncthreads();
    v.x = __expf(v.x - rowmax); v.y = __expf(v.y - rowmax);
    v.z = __expf(v.z - rowmax); v.w = __expf(v.w - rowmax);
    red[t] = v.x + v.y + v.z + v.w; __syncthreads();
    for (int s = 128; s > 0; s >>= 1) {
        if (t < s) red[t] += red[t + s];
        __syncthreads();
    }
    const float inv = 1.0f / red[0];
    v.x *= inv; v.y *= inv; v.z *= inv; v.w *= inv;
    ((float4*)p)[t] = v;
}

__global__ __launch_bounds__(256) void gemm_ctx(const float* __restrict__ attn,
                                                const float* __restrict__ vh,
                                                float* __restrict__ ctx) {
    __shared__ float As[16][LDS_PAD];
    __shared__ float Bs[16][LDS_PAD];
    const int t  = threadIdx.x;
    const int tx = t & 15, ty = t >> 4;
    const int bh = blockIdx.z;
    const int i0 = blockIdx.y * 64;
    const size_t abase = (size_t)bh * 1024 * 1024;
    const size_t base  = (size_t)bh * 1024 * 64;

    const int am = t >> 2, ak4 = t & 3;
    const int bk = t >> 4, bn4 = t & 15;

    float acc[4][4] = {};
    for (int k0 = 0; k0 < 1024; k0 += 16) {
        float4 a = *(const float4*)&attn[abase + (size_t)(i0 + am) * 1024 + k0 + ak4 * 4];
        float4 b = *(const float4*)&vh[base + (size_t)(k0 + bk) * 64 + bn4 * 4];
        As[ak4 * 4 + 0][am] = a.x; As[ak4 * 4 + 1][am] = a.y;
        As[ak4 * 4 + 2][am] = a.z; As[ak4 * 4 + 3][am] = a.w;
        Bs[bk][bn4 * 4 + 0] = b.x; Bs[bk][bn4 * 4 + 1] = b.y;
        Bs[bk][bn4 * 4 + 2] = b.z; Bs[bk][bn4 * 4 + 3] = b.w;
        __syncthreads();
#pragma unroll
        for (int kk = 0; kk < 16; ++kk) {
            float av[4], bv[4];
#pragma unroll
            for (int i = 0; i < 4; ++i) av[i] = As[kk][ty * 4 + i];
#pragma unroll
            for (int j = 0; j < 4; ++j) bv[j] = Bs[kk][tx * 4 + j];
#pragma unroll
            for (int i = 0; i < 4; ++i)
#pragma unroll
                for (int j = 0; j < 4; ++j) acc[i][j] += av[i] * bv[j];
        }
        __syncthreads();
    }
#pragma unroll
    for (int i = 0; i < 4; ++i) {
        float* dst = &ctx[base + (size_t)(i0 + ty * 4 + i) * 64];
#pragma unroll
        for (int j = 0; j < 4; ++j) dst[tx * 4 + j] = acc[i][j];
    }
}

__global__ __launch_bounds__(256) void gemm_out(const float* __restrict__ ctx,
                                                const float* __restrict__ wo,
                                                const float* __restrict__ bo,
                                                float* __restrict__ out) {
    __shared__ float As[16][LDS_PAD];
    __shared__ float Bs[16][LDS_PAD];
    const int t  = threadIdx.x;
    const int tx = t & 15, ty = t >> 4;
    const int row0 = blockIdx.y * 64;

    const int am = t >> 2, ak4 = t & 3;
    const int bk = t >> 4, bn4 = t & 15;

    float acc[4][4] = {};
    for (int k0 = 0; k0 < 1024; k0 += 16) {
        // A = concat(ctx): c = k0 + ak4*4 ; h = c>>6 ; d = c&63 (16-tile never crosses h)
        const int r = row0 + am;
        const int b = r >> 10, l = r & 1023;
        const int c = k0 + ak4 * 4;
        const int h = c >> 6, d = c & 63;
        float4 a = *(const float4*)&ctx[(size_t)((b * 16 + h) * 1024 + l) * 64 + d];
        float4 bvv = *(const float4*)&wo[(size_t)(k0 + bk) * 64 + bn4 * 4];
        As[ak4 * 4 + 0][am] = a.x; As[ak4 * 4 + 1][am] = a.y;
        As[ak4 * 4 + 2][am] = a.z; As[ak4 * 4 + 3][am] = a.w;
        Bs[bk][bn4 * 4 + 0] = bvv.x; Bs[bk][bn4 * 4 + 1] = bvv.y;
        Bs[bk][bn4 * 4 + 2] = bvv.z; Bs[bk][bn4 * 4 + 3] = bvv.w;
        __syncthreads();
#pragma unroll
        for (int kk = 0; kk < 16; ++kk) {
            float av[4], bv[4];
#pragma unroll
            for (int i = 0; i < 4; ++i) av[i] = As[kk][ty * 4 + i];
#pragma unroll
            for (int j = 0; j < 4; ++j) bv[j] = Bs[kk][tx * 4 + j];
#pragma unroll
            for (int i = 0; i < 4; ++i)
#pragma unroll
                for (int j = 0; j < 4; ++j) acc[i][j] += av[i] * bv[j];
        }
        __syncthreads();
    }
#pragma unroll
    for (int i = 0; i < 4; ++i) {
        const int r = row0 + ty * 4 + i;
#pragma unroll
        for (int j = 0; j < 4; ++j) {
            const int u = tx * 4 + j;
            out[(size_t)r * 64 + u] = acc[i][j] + bo[u];
        }
    }
}

extern "C" void kernel_launch(void* const* d_in, const int* in_sizes, int n_in,
                              void* d_out, int out_size, void* d_ws, size_t ws_size,
                              hipStream_t stream) {
    const float* v_in = (const float*)d_in[0];
    const float* k_in = (const float*)d_in[1];
    const float* q_in = (const float*)d_in[2];
    const float* wq   = (const float*)d_in[3];
    const float* bq   = (const float*)d_in[4];
    const float* wk   = (const float*)d_in[5];
    const float* bk   = (const float*)d_in[6];
    const float* wv   = (const float*)d_in[7];
    const float* bv   = (const float*)d_in[8];
    const float* wo   = (const float*)d_in[9];
    const float* bo   = (const float*)d_in[10];

    float* out  = (float*)d_out;
    float* attn = out + 262144;  // output 1 region (B,H,L,L)

    float* ws  = (float*)d_ws;   // need 64 MB
    float* qh  = ws;
    float* kh  = ws + 4194304;
    float* vh  = ws + 8388608;
    float* ctx = ws + 12582912;

    dim3 blk(256);
    gemm_proj<<<dim3(16, 64), blk, 0, stream>>>(q_in, wq, bq, qh);
    gemm_proj<<<dim3(16, 64), blk, 0, stream>>>(k_in, wk, bk, kh);
    gemm_proj<<<dim3(16, 64), blk, 0, stream>>>(v_in, wv, bv, vh);
    gemm_logits<<<dim3(16, 16, 64), blk, 0, stream>>>(qh, kh, attn);
    softmax_rows<<<dim3(65536), blk, 0, stream>>>(attn);
    gemm_ctx<<<dim3(1, 16, 64), blk, 0, stream>>>(attn, vh, ctx);
    gemm_out<<<dim3(1, 64), blk, 0, stream>>>(ctx, wo, bo, out);
}

// Round 2
// 738.154 us; speedup vs baseline: 1.4381x; 1.4381x over previous
//
#include <hip/hip_runtime.h>
#include <hip/hip_bf16.h>

// MultiHeadAttention  B=4, L=1024, H=16, U=64, D_IN=1024, D_MODEL=1024
// Round 1: bf16-split MFMA GEMMs + fused logits/softmax/attn/ctx kernel.
//
// Pipeline:
//   pack_wt      x3 : W(1024x1024 fp32) -> Wt_hi/Wt_lo bf16, transposed [n][k]
//   gemm_proj    x3 : X @ W + b -> head-split bf16; Q/K: hi+lo split (3-pass MFMA),
//                     V: single bf16 (1-pass)
//   trans_vh        : vh[bh][l][u] -> vhT[bh][u][l]  (B-operand layout for ctx MFMA)
//   attn_fused      : per (bh, 16 q-rows): logits (split MFMA) -> 16x1024 fp32 tile
//                     in LDS (XOR-swizzled) -> softmax (wave shuffles) -> write attn
//                     (268 MB, once) -> ctx = P@V via MFMA (P cvt from LDS)
//   gemm_out        : concat(ctx fp32) @ wo + bo (fp32 vector; only 0.5 GFLOP)
//
// Precision: split bf16 (hi=rne(x), lo=rne(x-hi)) keeps the Q/K/logit path at
// ~2^-17 relative error; softmax itself is exact fp32. V path single bf16:
// errors enter ctx weighted by sqrt(sum p^2) << 1.

typedef __attribute__((ext_vector_type(8))) short s8v;   // 8 bf16 = 4 VGPR
typedef __attribute__((ext_vector_type(4))) float f4v;   // MFMA C/D

#define MFMA16(a, b, c) __builtin_amdgcn_mfma_f32_16x16x32_bf16(a, b, c, 0, 0, 0)

__device__ __forceinline__ ushort f2bf(float x) {
    unsigned u = __float_as_uint(x);
    return (ushort)((u + 0x7FFF + ((u >> 16) & 1)) >> 16);  // RNE
}
__device__ __forceinline__ void split2(float x, ushort& h, ushort& l) {
    h = f2bf(x);
    float hf = __uint_as_float(((unsigned)h) << 16);
    l = f2bf(x - hf);
}

// ---------------------------------------------------------------- pack_wt ----
// W[k][n] fp32 -> Wt_hi[n][k], Wt_lo[n][k] bf16 (transpose + split), 1024x1024.
__global__ __launch_bounds__(256) void pack_wt(const float* __restrict__ W,
                                               ushort* __restrict__ Wt_hi,
                                               ushort* __restrict__ Wt_lo) {
    __shared__ float tile[32][36];
    const int t = threadIdx.x;
    const int n0 = blockIdx.x * 32, k0 = blockIdx.y * 32;
    {
        const int kr = t >> 3, c4 = (t & 7) * 4;
        float4 v = *(const float4*)&W[(size_t)(k0 + kr) * 1024 + n0 + c4];
        *(float4*)&tile[kr][c4] = v;
    }
    __syncthreads();
    {
        const int n = t >> 3, k4 = (t & 7) * 4;
        ushort4 h, l;
        split2(tile[k4 + 0][n], h.x, l.x);
        split2(tile[k4 + 1][n], h.y, l.y);
        split2(tile[k4 + 2][n], h.z, l.z);
        split2(tile[k4 + 3][n], h.w, l.w);
        *(ushort4*)&Wt_hi[(size_t)(n0 + n) * 1024 + k0 + k4] = h;
        *(ushort4*)&Wt_lo[(size_t)(n0 + n) * 1024 + k0 + k4] = l;
    }
}

// -------------------------------------------------------------- gemm_proj ----
// X(4096x1024 fp32) @ W (via Wt bf16 [n][k]) + bias -> head-split bf16 out.
// 128x128 tile, BK=32, 256 thr (4 waves, each 64x64 = 4x4 tiles of 16x16x32).
// LDS rows padded to 40 bf16 (80 B) -> frag b128 reads are 2-way max (free).
#define PROJ_LDSTRIDE 40
template <bool SPLIT>
__global__ __launch_bounds__(256, 2) void gemm_proj_mfma(
    const float* __restrict__ X, const ushort* __restrict__ Wt_hi,
    const ushort* __restrict__ Wt_lo, const float* __restrict__ bias,
    ushort* __restrict__ Yhi, ushort* __restrict__ Ylo) {
    __shared__ ushort As_hi[128 * PROJ_LDSTRIDE];
    __shared__ ushort As_lo[128 * PROJ_LDSTRIDE];
    __shared__ ushort Bs_hi[128 * PROJ_LDSTRIDE];
    __shared__ ushort Bs_lo[128 * PROJ_LDSTRIDE];

    const int t = threadIdx.x;
    const int lane = t & 63, w = t >> 6;
    const int wm = (w & 1) * 64, wn = (w >> 1) * 64;
    const int fr = lane & 15, q8 = (lane >> 4) * 8;
    const int row0 = blockIdx.y * 128, col0 = blockIdx.x * 128;

    const int srow = t >> 1, skb = (t & 1) * 16;  // stager: row, k-base (16 wide)

    f4v acc[4][4] = {};

    for (int k0 = 0; k0 < 1024; k0 += 32) {
        // ---- stage A: fp32 -> hi/lo bf16
        {
            const float* xp = &X[(size_t)(row0 + srow) * 1024 + k0 + skb];
#pragma unroll
            for (int j = 0; j < 4; ++j) {
                float4 x4 = *(const float4*)&xp[4 * j];
                ushort4 h, l;
                split2(x4.x, h.x, l.x);
                split2(x4.y, h.y, l.y);
                split2(x4.z, h.z, l.z);
                split2(x4.w, h.w, l.w);
                *(ushort4*)&As_hi[srow * PROJ_LDSTRIDE + skb + 4 * j] = h;
                if (SPLIT) *(ushort4*)&As_lo[srow * PROJ_LDSTRIDE + skb + 4 * j] = l;
            }
        }
        // ---- stage B: bf16 already packed
        {
            const ushort* bp = &Wt_hi[(size_t)(col0 + srow) * 1024 + k0 + skb];
            *(uint4*)&Bs_hi[srow * PROJ_LDSTRIDE + skb] = *(const uint4*)bp;
            *(uint4*)&Bs_hi[srow * PROJ_LDSTRIDE + skb + 8] = *(const uint4*)(bp + 8);
            if (SPLIT) {
                const ushort* bl = &Wt_lo[(size_t)(col0 + srow) * 1024 + k0 + skb];
                *(uint4*)&Bs_lo[srow * PROJ_LDSTRIDE + skb] = *(const uint4*)bl;
                *(uint4*)&Bs_lo[srow * PROJ_LDSTRIDE + skb + 8] = *(const uint4*)(bl + 8);
            }
        }
        __syncthreads();

        s8v a_hi[4], a_lo[4], b_hi[4], b_lo[4];
#pragma unroll
        for (int mi = 0; mi < 4; ++mi) {
            a_hi[mi] = *(const s8v*)&As_hi[(wm + mi * 16 + fr) * PROJ_LDSTRIDE + q8];
            if (SPLIT) a_lo[mi] = *(const s8v*)&As_lo[(wm + mi * 16 + fr) * PROJ_LDSTRIDE + q8];
        }
#pragma unroll
        for (int ni = 0; ni < 4; ++ni) {
            b_hi[ni] = *(const s8v*)&Bs_hi[(wn + ni * 16 + fr) * PROJ_LDSTRIDE + q8];
            if (SPLIT) b_lo[ni] = *(const s8v*)&Bs_lo[(wn + ni * 16 + fr) * PROJ_LDSTRIDE + q8];
        }
#pragma unroll
        for (int mi = 0; mi < 4; ++mi)
#pragma unroll
            for (int ni = 0; ni < 4; ++ni) {
                acc[mi][ni] = MFMA16(a_hi[mi], b_hi[ni], acc[mi][ni]);
                if (SPLIT) {
                    acc[mi][ni] = MFMA16(a_hi[mi], b_lo[ni], acc[mi][ni]);
                    acc[mi][ni] = MFMA16(a_lo[mi], b_hi[ni], acc[mi][ni]);
                }
            }
        __syncthreads();
    }

    // epilogue: head-split bf16 store (+ lo for SPLIT)
#pragma unroll
    for (int mi = 0; mi < 4; ++mi)
#pragma unroll
        for (int ni = 0; ni < 4; ++ni)
#pragma unroll
            for (int r = 0; r < 4; ++r) {
                const int lr = wm + mi * 16 + (lane >> 4) * 4 + r;
                const int lc = wn + ni * 16 + fr;
                const int grow = row0 + lr;
                const int b = grow >> 10, ll = grow & 1023;
                const int gcol = col0 + lc;
                const int h = gcol >> 6, u = gcol & 63;
                const float val = acc[mi][ni][r] + bias[gcol];
                const size_t o = ((size_t)((b * 16 + h) * 1024 + ll)) * 64 + u;
                if (SPLIT) {
                    ushort hh, lll;
                    split2(val, hh, lll);
                    Yhi[o] = hh;
                    Ylo[o] = lll;
                } else {
                    Yhi[o] = f2bf(val);
                }
            }
}

// --------------------------------------------------------------- trans_vh ----
// vh[bh][l][u] bf16 -> vhT[bh][u][l] bf16 (B-operand layout for ctx MFMA).
__global__ __launch_bounds__(256) void trans_vh(const ushort* __restrict__ vh,
                                                ushort* __restrict__ vhT) {
    __shared__ ushort st[64][72];
    const int t = threadIdx.x;
    const int bh = blockIdx.y, l0 = blockIdx.x * 64;
    {
        const int l = t >> 2, uc = (t & 3) * 16;
        const ushort* src = &vh[((size_t)bh * 1024 + l0 + l) * 64 + uc];
        *(uint4*)&st[l][uc] = *(const uint4*)src;
        *(uint4*)&st[l][uc + 8] = *(const uint4*)(src + 8);
    }
    __syncthreads();
    {
        const int u = t >> 2, lc = (t & 3) * 16;
        ushort tmp[16];
#pragma unroll
        for (int i = 0; i < 16; ++i) tmp[i] = st[lc + i][u];
        ushort* dst = &vhT[((size_t)bh * 64 + u) * 1024 + l0 + lc];
        *(uint4*)dst = *(uint4*)&tmp[0];
        *(uint4*)(dst + 8) = *(uint4*)&tmp[8];
    }
}

// ------------------------------------------------------------- attn_fused ----
// Per block: bh = blockIdx.y, 16 q-rows. Logits via split MFMA into 64 KB LDS
// (fp32, XOR-swizzled groups of 4), softmax via wave shuffles, attn write,
// ctx = P @ V via single-pass MFMA reading P from LDS (cvt to bf16).
__device__ __forceinline__ int swz(int row, int c) {
    return row * 1024 + ((((c >> 2) ^ (row & 7)) << 2) | (c & 3));
}

__global__ __launch_bounds__(256, 2) void attn_fused(
    const ushort* __restrict__ qh_hi, const ushort* __restrict__ qh_lo,
    const ushort* __restrict__ kh_hi, const ushort* __restrict__ kh_lo,
    const ushort* __restrict__ vhT, float* __restrict__ attn,
    float* __restrict__ ctx) {
    __shared__ float probs[16 * 1024];  // 64 KB

    const int t = threadIdx.x, lane = t & 63, w = t >> 6;
    const int bh = blockIdx.y, q0 = blockIdx.x * 16;
    const int fr = lane & 15, q8 = (lane >> 4) * 8;
    const size_t hbase = (size_t)bh * 1024 * 64;

    // Q fragments (row = q0+fr), k in [0,32) and [32,64)
    const ushort* qp = &qh_hi[hbase + (size_t)(q0 + fr) * 64];
    const ushort* ql = &qh_lo[hbase + (size_t)(q0 + fr) * 64];
    const s8v qa_h0 = *(const s8v*)(qp + q8), qa_h1 = *(const s8v*)(qp + 32 + q8);
    const s8v qa_l0 = *(const s8v*)(ql + q8), qa_l1 = *(const s8v*)(ql + 32 + q8);

    // ---- logits: wave w handles n-tiles {w, w+4, ..., w+60}
    for (int i = 0; i < 16; ++i) {
        const int nt = w + i * 4;
        const ushort* kp = &kh_hi[hbase + (size_t)(nt * 16 + fr) * 64];
        const ushort* kl = &kh_lo[hbase + (size_t)(nt * 16 + fr) * 64];
        const s8v kb_h0 = *(const s8v*)(kp + q8), kb_h1 = *(const s8v*)(kp + 32 + q8);
        const s8v kb_l0 = *(const s8v*)(kl + q8), kb_l1 = *(const s8v*)(kl + 32 + q8);
        f4v a0 = {}, a1 = {}, a2 = {};
        a0 = MFMA16(qa_h0, kb_h0, a0);
        a0 = MFMA16(qa_h1, kb_h1, a0);
        a1 = MFMA16(qa_h0, kb_l0, a1);
        a1 = MFMA16(qa_h1, kb_l1, a1);
        a2 = MFMA16(qa_l0, kb_h0, a2);
        a2 = MFMA16(qa_l1, kb_h1, a2);
#pragma unroll
        for (int r = 0; r < 4; ++r) {
            const int row = (lane >> 4) * 4 + r;
            const int c = nt * 16 + fr;
            probs[swz(row, c)] = (a0[r] + a1[r] + a2[r]) * 0.125f;
        }
    }
    __syncthreads();

    // ---- softmax: wave w owns rows 4w..4w+3 (fp32 exact, wave shuffles)
    for (int rr = 0; rr < 4; ++rr) {
        const int row = w * 4 + rr;
        float v[16];
#pragma unroll
        for (int j = 0; j < 16; ++j) v[j] = probs[swz(row, lane + j * 64)];
        float m = v[0];
#pragma unroll
        for (int j = 1; j < 16; ++j) m = fmaxf(m, v[j]);
        for (int off = 32; off > 0; off >>= 1) m = fmaxf(m, __shfl_xor(m, off));
        float s = 0.f;
#pragma unroll
        for (int j = 0; j < 16; ++j) {
            v[j] = __expf(v[j] - m);
            s += v[j];
        }
        for (int off = 32; off > 0; off >>= 1) s += __shfl_xor(s, off);
        const float inv = 1.0f / s;
        float* arow = &attn[((size_t)bh << 20) + (size_t)(q0 + row) * 1024];
#pragma unroll
        for (int j = 0; j < 16; ++j) {
            const float p = v[j] * inv;
            probs[swz(row, lane + j * 64)] = p;
            arow[lane + j * 64] = p;
        }
    }
    __syncthreads();

    // ---- ctx: wave w -> u-tile w (cols 16w..16w+15), P from LDS cvt to bf16
    f4v cacc = {};
    const ushort* vp = &vhT[hbase + (size_t)(w * 16 + fr) * 1024];
    for (int ks = 0; ks < 32; ++ks) {
        const int k0 = ks * 32 + q8;
        const float4 pa = *(const float4*)&probs[swz(fr, k0)];
        const float4 pb = *(const float4*)&probs[swz(fr, k0 + 4)];
        s8v a;
        a[0] = (short)f2bf(pa.x); a[1] = (short)f2bf(pa.y);
        a[2] = (short)f2bf(pa.z); a[3] = (short)f2bf(pa.w);
        a[4] = (short)f2bf(pb.x); a[5] = (short)f2bf(pb.y);
        a[6] = (short)f2bf(pb.z); a[7] = (short)f2bf(pb.w);
        const s8v b = *(const s8v*)(vp + ks * 32 + q8);
        cacc = MFMA16(a, b, cacc);
    }
#pragma unroll
    for (int r = 0; r < 4; ++r) {
        const int row = (lane >> 4) * 4 + r;
        ctx[((size_t)bh * 1024 + q0 + row) * 64 + w * 16 + fr] = cacc[r];
    }
}

// --------------------------------------------------------------- gemm_out ----
// concat(ctx fp32) @ wo + bo (fp32 vector path; 0.54 GFLOP)
#define LDS_PAD 68
__global__ __launch_bounds__(256) void gemm_out(const float* __restrict__ ctx,
                                                const float* __restrict__ wo,
                                                const float* __restrict__ bo,
                                                float* __restrict__ out) {
    __shared__ float As[16][LDS_PAD];
    __shared__ float Bs[16][LDS_PAD];
    const int t = threadIdx.x;
    const int tx = t & 15, ty = t >> 4;
    const int row0 = blockIdx.y * 64;

    const int am = t >> 2, ak4 = t & 3;
    const int bk = t >> 4, bn4 = t & 15;

    float acc[4][4] = {};
    for (int k0 = 0; k0 < 1024; k0 += 16) {
        const int r = row0 + am;
        const int b = r >> 10, l = r & 1023;
        const int c = k0 + ak4 * 4;
        const int h = c >> 6, d = c & 63;
        float4 a = *(const float4*)&ctx[(size_t)((b * 16 + h) * 1024 + l) * 64 + d];
        float4 bvv = *(const float4*)&wo[(size_t)(k0 + bk) * 64 + bn4 * 4];
        As[ak4 * 4 + 0][am] = a.x; As[ak4 * 4 + 1][am] = a.y;
        As[ak4 * 4 + 2][am] = a.z; As[ak4 * 4 + 3][am] = a.w;
        Bs[bk][bn4 * 4 + 0] = bvv.x; Bs[bk][bn4 * 4 + 1] = bvv.y;
        Bs[bk][bn4 * 4 + 2] = bvv.z; Bs[bk][bn4 * 4 + 3] = bvv.w;
        __syncthreads();
#pragma unroll
        for (int kk = 0; kk < 16; ++kk) {
            float av[4], bv[4];
#pragma unroll
            for (int i = 0; i < 4; ++i) av[i] = As[kk][ty * 4 + i];
#pragma unroll
            for (int j = 0; j < 4; ++j) bv[j] = Bs[kk][tx * 4 + j];
#pragma unroll
            for (int i = 0; i < 4; ++i)
#pragma unroll
                for (int j = 0; j < 4; ++j) acc[i][j] += av[i] * bv[j];
        }
        __syncthreads();
    }
#pragma unroll
    for (int i = 0; i < 4; ++i) {
        const int r = row0 + ty * 4 + i;
#pragma unroll
        for (int j = 0; j < 4; ++j) {
            const int u = tx * 4 + j;
            out[(size_t)r * 64 + u] = acc[i][j] + bo[u];
        }
    }
}

extern "C" void kernel_launch(void* const* d_in, const int* in_sizes, int n_in,
                              void* d_out, int out_size, void* d_ws, size_t ws_size,
                              hipStream_t stream) {
    const float* v_in = (const float*)d_in[0];
    const float* k_in = (const float*)d_in[1];
    const float* q_in = (const float*)d_in[2];
    const float* wq = (const float*)d_in[3];
    const float* bq = (const float*)d_in[4];
    const float* wk = (const float*)d_in[5];
    const float* bk = (const float*)d_in[6];
    const float* wv = (const float*)d_in[7];
    const float* bv = (const float*)d_in[8];
    const float* wo = (const float*)d_in[9];
    const float* bo = (const float*)d_in[10];

    float* out = (float*)d_out;
    float* attn = out + 262144;

    char* w8 = (char*)d_ws;
    const size_t MB = 1u << 20;
    ushort* wtq_hi = (ushort*)(w8 + 0 * MB);
    ushort* wtq_lo = (ushort*)(w8 + 2 * MB);
    ushort* wtk_hi = (ushort*)(w8 + 4 * MB);
    ushort* wtk_lo = (ushort*)(w8 + 6 * MB);
    ushort* wtv_hi = (ushort*)(w8 + 8 * MB);
    ushort* wtv_lo = (ushort*)(w8 + 10 * MB);
    ushort* qh_hi = (ushort*)(w8 + 12 * MB);
    ushort* qh_lo = (ushort*)(w8 + 20 * MB);
    ushort* kh_hi = (ushort*)(w8 + 28 * MB);
    ushort* kh_lo = (ushort*)(w8 + 36 * MB);
    ushort* vh_hi = (ushort*)(w8 + 44 * MB);
    ushort* vh_lo = (ushort*)(w8 + 52 * MB);
    ushort* vhT = (ushort*)(w8 + 60 * MB);
    float* ctx = (float*)(w8 + 68 * MB);

    dim3 blk(256);
    pack_wt<<<dim3(32, 32), blk, 0, stream>>>(wq, wtq_hi, wtq_lo);
    pack_wt<<<dim3(32, 32), blk, 0, stream>>>(wk, wtk_hi, wtk_lo);
    pack_wt<<<dim3(32, 32), blk, 0, stream>>>(wv, wtv_hi, wtv_lo);

    gemm_proj_mfma<true><<<dim3(8, 32), blk, 0, stream>>>(q_in, wtq_hi, wtq_lo, bq, qh_hi, qh_lo);
    gemm_proj_mfma<true><<<dim3(8, 32), blk, 0, stream>>>(k_in, wtk_hi, wtk_lo, bk, kh_hi, kh_lo);
    gemm_proj_mfma<false><<<dim3(8, 32), blk, 0, stream>>>(v_in, wtv_hi, wtv_lo, bv, vh_hi, vh_lo);

    trans_vh<<<dim3(16, 64), blk, 0, stream>>>(vh_hi, vhT);

    attn_fused<<<dim3(64, 64), blk, 0, stream>>>(qh_hi, qh_lo, kh_hi, kh_lo, vhT, attn, ctx);

    gemm_out<<<dim3(1, 64), blk, 0, stream>>>(ctx, wo, bo, out);
}